// Round 14
// baseline (60.683 us; speedup 1.0000x reference)
//
#include <hip/hip_runtime.h>
#include <hip/hip_bf16.h>

#define HID   128
#define PBLK  64
#define NPIX  (256*512)
#define L2E2  2.88539008177792681f   // 2*log2(e)

typedef __attribute__((ext_vector_type(8))) short bf16x8;
typedef __attribute__((ext_vector_type(4))) float f32x4;

#if __has_builtin(__builtin_amdgcn_exp2f)
__device__ inline float fexp2(float x) { return __builtin_amdgcn_exp2f(x); }
#else
__device__ inline float fexp2(float x) { return exp2f(x); }
#endif

__device__ inline unsigned pack2(float a, float b) {
    __hip_bfloat16 lo = __float2bfloat16(a);
    __hip_bfloat16 hi = __float2bfloat16(b);
    unsigned short ul = *reinterpret_cast<unsigned short*>(&lo);
    unsigned short uh = *reinterpret_cast<unsigned short*>(&hi);
    return (unsigned)ul | ((unsigned)uh << 16);
}
__device__ inline float ulo(unsigned u) { union { unsigned u; float f; } v; v.u = u << 16;        return v.f; }
__device__ inline float uhi(unsigned u) { union { unsigned u; float f; } v; v.u = u & 0xffff0000u; return v.f; }

// tanh(z) where u = 2*log2e*z already folded into operands
__device__ inline float actf(float u) {
    float e = fexp2(u);
    return 1.0f - 2.0f * __builtin_amdgcn_rcpf(e + 1.0f);
}

__device__ inline bf16x8 bc(uint4 v) { return __builtin_bit_cast(bf16x8, v); }

__device__ __forceinline__ uint2 quadact(f32x4 a, uint2 rec, float4 bet) {
    float v0 = actf(fmaf(bet.x, ulo(rec.x), a[0]));
    float v1 = actf(fmaf(bet.y, uhi(rec.x), a[1]));
    float v2 = actf(fmaf(bet.z, ulo(rec.y), a[2]));
    float v3 = actf(fmaf(bet.w, uhi(rec.y), a[3]));
    return make_uint2(pack2(v0, v1), pack2(v2, v3));
}

// ---- prologue: W_h / W_out -> frag-ordered bf16 in ws, rows pre-scaled by 2log2e*resp ----
// chunk# = ((lay*4 + rt2)*2 + aidx)*4 + kb (verified layout)
__global__ __launch_bounds__(256) void prep_weights(
    const float* __restrict__ W_h, const float* __restrict__ W_out,
    const float* __restrict__ resp, const float* __restrict__ resp_out,
    unsigned short* __restrict__ ws)
{
    int c = blockIdx.x * 256 + threadIdx.x;
    if (c < 4096) {
        int l = c & 63, kb = (c >> 6) & 3, aidx = (c >> 8) & 1, rt2 = (c >> 9) & 3, lay = (c >> 11) & 1;
        int row = rt2 * 32 + aidx * 16 + (l & 15);
        int k   = kb * 32 + (l >> 4) * 8;
        float al = L2E2 * resp[(lay + 1) * HID + row];
        const float* src = W_h + (lay * HID + row) * HID + k;
        float4 f0 = *(const float4*)src, f1 = *(const float4*)(src + 4);
        uint4 v;
        v.x = pack2(al * f0.x, al * f0.y); v.y = pack2(al * f0.z, al * f0.w);
        v.z = pack2(al * f1.x, al * f1.y); v.w = pack2(al * f1.z, al * f1.w);
        *(uint4*)(ws + (size_t)c * 8) = v;
    } else if (c < 4352) {
        int c2 = c - 4096, l = c2 & 63, kb = c2 >> 6;
        int row = l & 15, k = kb * 32 + (l >> 4) * 8;
        uint4 v = {0u, 0u, 0u, 0u};
        if (row < 3) {
            float al = L2E2 * resp_out[row];
            const float* src = W_out + row * HID + k;
            float4 f0 = *(const float4*)src, f1 = *(const float4*)(src + 4);
            v.x = pack2(al * f0.x, al * f0.y); v.y = pack2(al * f0.z, al * f0.w);
            v.z = pack2(al * f1.x, al * f1.y); v.w = pack2(al * f1.z, al * f1.w);
        }
        *(uint4*)(ws + 32768 + (size_t)c2 * 8) = v;
    }
}

// 512 threads, 8 waves, 64 px/block, ~38 KB LDS (NO weights in LDS -> room for
// 3-4 co-resident blocks). Both W layers streamed from the L2-hot ws image,
// issued one region ahead (r8 pattern). Occupancy is the experiment.
__global__ __launch_bounds__(512) void fused_net(
    const float* __restrict__ x_in,     // [3][NPIX]
    const float* __restrict__ W_in,     // [128][3]
    const float* __restrict__ r_rec,    // [3][128]
    const float* __restrict__ resp,     // [3][128]
    const float* __restrict__ bias,     // [3][128]
    const float* __restrict__ b_out,    // [3]
    const int*   __restrict__ n_iters_p,
    const unsigned short* __restrict__ wsw,
    float* __restrict__ out)            // [3][NPIX]
{
    __shared__ __align__(16) unsigned short P0s[4 * 4 * 64 * 8]; // 16384 B
    __shared__ __align__(16) unsigned short P1s[4 * 4 * 64 * 8]; // 16384 B
    __shared__ float4 Winp_s[HID];      // {a*w0,a*w1,a*w2,gamma0}, a = L2E2*resp0
    __shared__ float  beta_s[3 * HID];  // L2E2*resp*r_rec
    __shared__ float  gamma_s[2 * HID]; // L2E2*bias layers 1,2
    __shared__ float  gammao_s[16];     // L2E2*b_out zero-padded
    __shared__ float  xs[3 * PBLK];

    const int t = threadIdx.x;
    const int w = t >> 6, l = t & 63;
    const int lr = l & 15, lg = l >> 4;
    const int rt2 = w >> 1;            // row-tile 0..3 (32 rows)
    const int ct  = w & 1;             // px-tile 0..1 (32 px)
    const int pixbase = (int)blockIdx.x * PBLK;
    const int niters = *n_iters_p;
    const uint4* wsU = (const uint4*)wsw;

    // ---- stage params + inputs (no W staging at all) ----
    if (t < 3 * HID) beta_s[t] = L2E2 * resp[t] * r_rec[t];
    if (t < 2 * HID) gamma_s[t] = L2E2 * bias[HID + t];
    if (t < HID) {
        float a = L2E2 * resp[t];
        float4 pv;
        pv.x = a * W_in[t * 3 + 0];
        pv.y = a * W_in[t * 3 + 1];
        pv.z = a * W_in[t * 3 + 2];
        pv.w = L2E2 * bias[t];
        Winp_s[t] = pv;
    }
    if (t < 16) gammao_s[t] = (t < 3) ? L2E2 * b_out[t] : 0.0f;
    if (t < 3 * PBLK) xs[t] = x_in[(t >> 6) * NPIX + pixbase + (t & 63)];
    __syncthreads();

    const int p0 = t & 63, hb2 = t >> 6;
    const float x0 = xs[p0], x1 = xs[64 + p0], x2 = xs[128 + p0];

    unsigned rec0[8];
    uint2 rec1_00{0,0}, rec1_01{0,0}, rec1_10{0,0}, rec1_11{0,0};
    uint2 rec2_00{0,0}, rec2_01{0,0}, rec2_10{0,0}, rec2_11{0,0};
    #pragma unroll
    for (int i = 0; i < 8; ++i) rec0[i] = 0u;

    const bf16x8* P0c = (const bf16x8*)P0s;
    const bf16x8* P1c = (const bf16x8*)P1s;
    const uint4* WA0 = wsU + rt2 * 512 + l;          // layer-1 A frags (global, L2-hot)
    const uint4* WA1 = wsU + (4 + rt2) * 512 + l;    // layer-2 A frags

    const float4 bt1A = *(const float4*)(beta_s + HID + rt2 * 32 + lg * 4);
    const float4 bt1B = *(const float4*)(beta_s + HID + rt2 * 32 + 16 + lg * 4);
    const float4 bt2A = *(const float4*)(beta_s + 2 * HID + rt2 * 32 + lg * 4);
    const float4 bt2B = *(const float4*)(beta_s + 2 * HID + rt2 * 32 + 16 + lg * 4);
    const float4 gm1A = *(const float4*)(gamma_s + rt2 * 32 + lg * 4);
    const float4 gm1B = *(const float4*)(gamma_s + rt2 * 32 + 16 + lg * 4);
    const float4 gm2A = *(const float4*)(gamma_s + HID + rt2 * 32 + lg * 4);
    const float4 gm2B = *(const float4*)(gamma_s + HID + rt2 * 32 + 16 + lg * 4);

    const int wr00 = (((ct * 2 + 0) * 4 + rt2) * 64 + (0 + (lg >> 1)) * 16 + lr) * 8 + (lg & 1) * 4;
    const int wr01 = (((ct * 2 + 1) * 4 + rt2) * 64 + (0 + (lg >> 1)) * 16 + lr) * 8 + (lg & 1) * 4;
    const int wr10 = (((ct * 2 + 0) * 4 + rt2) * 64 + (2 + (lg >> 1)) * 16 + lr) * 8 + (lg & 1) * 4;
    const int wr11 = (((ct * 2 + 1) * 4 + rt2) * 64 + (2 + (lg >> 1)) * 16 + lr) * 8 + (lg & 1) * 4;

    for (int it = 0; it < niters; ++it) {
        // opaque per-iter pointers: stop LICM from hoisting the weight loads
        // into 64 persistent registers (the r3/r9 spill trap)
        const uint4* wa0 = WA0;
        const uint4* wa1 = WA1;
        asm volatile("" : "+v"(wa0), "+v"(wa1));

        // issue layer-1 A loads: in flight across the L0 VALU phase
        uint4 ga0 = wa0[0 * 64], ga1 = wa0[1 * 64], ga2 = wa0[2 * 64], ga3 = wa0[3 * 64];
        uint4 ga4 = wa0[4 * 64], ga5 = wa0[5 * 64], ga6 = wa0[6 * 64], ga7 = wa0[7 * 64];

        // ---- L0: leaves -> h0 (VALU), frag-ordered write into P0 ----
        #pragma unroll
        for (int s = 0; s < 2; ++s) {
            uint4 ov;
            #pragma unroll
            for (int q = 0; q < 4; ++q) {
                int c = s * 8 + q * 2, h = hb2 * 16 + c;
                float4 wp0 = Winp_s[h], wp1 = Winp_s[h + 1];
                float bet0 = beta_s[h], bet1 = beta_s[h + 1];
                unsigned rp = rec0[s * 4 + q];
                float c1a = fmaf(wp0.x, x0, fmaf(wp0.y, x1, fmaf(wp0.z, x2, wp0.w)));
                float c1b = fmaf(wp1.x, x0, fmaf(wp1.y, x1, fmaf(wp1.z, x2, wp1.w)));
                float v0 = actf(fmaf(bet0, ulo(rp), c1a));
                float v1 = actf(fmaf(bet1, uhi(rp), c1b));
                unsigned pk = pack2(v0, v1);
                rec0[s * 4 + q] = pk;
                if (q == 0) ov.x = pk; else if (q == 1) ov.y = pk;
                else if (q == 2) ov.z = pk; else ov.w = pk;
            }
            int h8 = hb2 * 16 + s * 8;
            int chunk = ((p0 >> 4) * 4 + (h8 >> 5)) * 64 + ((h8 >> 3) & 3) * 16 + (p0 & 15);
            *(uint4*)(P0s + chunk * 8) = ov;
        }
        __syncthreads();

        // ---- layer 1: P0 -> P1 (A = ga, consumed); then issue layer-2 loads ----
        {
            const bf16x8* SB = P0c + (ct * 8) * 64 + l;
            f32x4 acc0{gm1A.x, gm1A.y, gm1A.z, gm1A.w};
            f32x4 acc1 = acc0;
            f32x4 acc2{gm1B.x, gm1B.y, gm1B.z, gm1B.w};
            f32x4 acc3 = acc2;
            bf16x8 b0, b1;
            b0 = SB[0 * 64]; b1 = SB[4 * 64];
            acc0 = __builtin_amdgcn_mfma_f32_16x16x32_bf16(bc(ga0), b0, acc0, 0, 0, 0);
            acc1 = __builtin_amdgcn_mfma_f32_16x16x32_bf16(bc(ga0), b1, acc1, 0, 0, 0);
            acc2 = __builtin_amdgcn_mfma_f32_16x16x32_bf16(bc(ga4), b0, acc2, 0, 0, 0);
            acc3 = __builtin_amdgcn_mfma_f32_16x16x32_bf16(bc(ga4), b1, acc3, 0, 0, 0);
            b0 = SB[1 * 64]; b1 = SB[5 * 64];
            acc0 = __builtin_amdgcn_mfma_f32_16x16x32_bf16(bc(ga1), b0, acc0, 0, 0, 0);
            acc1 = __builtin_amdgcn_mfma_f32_16x16x32_bf16(bc(ga1), b1, acc1, 0, 0, 0);
            acc2 = __builtin_amdgcn_mfma_f32_16x16x32_bf16(bc(ga5), b0, acc2, 0, 0, 0);
            acc3 = __builtin_amdgcn_mfma_f32_16x16x32_bf16(bc(ga5), b1, acc3, 0, 0, 0);
            b0 = SB[2 * 64]; b1 = SB[6 * 64];
            acc0 = __builtin_amdgcn_mfma_f32_16x16x32_bf16(bc(ga2), b0, acc0, 0, 0, 0);
            acc1 = __builtin_amdgcn_mfma_f32_16x16x32_bf16(bc(ga2), b1, acc1, 0, 0, 0);
            acc2 = __builtin_amdgcn_mfma_f32_16x16x32_bf16(bc(ga6), b0, acc2, 0, 0, 0);
            acc3 = __builtin_amdgcn_mfma_f32_16x16x32_bf16(bc(ga6), b1, acc3, 0, 0, 0);
            b0 = SB[3 * 64]; b1 = SB[7 * 64];
            acc0 = __builtin_amdgcn_mfma_f32_16x16x32_bf16(bc(ga3), b0, acc0, 0, 0, 0);
            acc1 = __builtin_amdgcn_mfma_f32_16x16x32_bf16(bc(ga3), b1, acc1, 0, 0, 0);
            acc2 = __builtin_amdgcn_mfma_f32_16x16x32_bf16(bc(ga7), b0, acc2, 0, 0, 0);
            acc3 = __builtin_amdgcn_mfma_f32_16x16x32_bf16(bc(ga7), b1, acc3, 0, 0, 0);

            // issue layer-2 A loads: in flight across the epilogue + barrier
            ga0 = wa1[0 * 64]; ga1 = wa1[1 * 64]; ga2 = wa1[2 * 64]; ga3 = wa1[3 * 64];
            ga4 = wa1[4 * 64]; ga5 = wa1[5 * 64]; ga6 = wa1[6 * 64]; ga7 = wa1[7 * 64];

            rec1_00 = quadact(acc0, rec1_00, bt1A);
            rec1_01 = quadact(acc1, rec1_01, bt1A);
            rec1_10 = quadact(acc2, rec1_10, bt1B);
            rec1_11 = quadact(acc3, rec1_11, bt1B);
            *(uint2*)(P1s + wr00) = rec1_00;
            *(uint2*)(P1s + wr01) = rec1_01;
            *(uint2*)(P1s + wr10) = rec1_10;
            *(uint2*)(P1s + wr11) = rec1_11;
        }
        __syncthreads();

        // ---- layer 2: P1 -> regs (A = gb in ga regs); P0 write last iter only ----
        {
            const bool last = (it == niters - 1);
            const bf16x8* SB = P1c + (ct * 8) * 64 + l;
            f32x4 acc0{gm2A.x, gm2A.y, gm2A.z, gm2A.w};
            f32x4 acc1 = acc0;
            f32x4 acc2{gm2B.x, gm2B.y, gm2B.z, gm2B.w};
            f32x4 acc3 = acc2;
            bf16x8 b0, b1;
            b0 = SB[0 * 64]; b1 = SB[4 * 64];
            acc0 = __builtin_amdgcn_mfma_f32_16x16x32_bf16(bc(ga0), b0, acc0, 0, 0, 0);
            acc1 = __builtin_amdgcn_mfma_f32_16x16x32_bf16(bc(ga0), b1, acc1, 0, 0, 0);
            acc2 = __builtin_amdgcn_mfma_f32_16x16x32_bf16(bc(ga4), b0, acc2, 0, 0, 0);
            acc3 = __builtin_amdgcn_mfma_f32_16x16x32_bf16(bc(ga4), b1, acc3, 0, 0, 0);
            b0 = SB[1 * 64]; b1 = SB[5 * 64];
            acc0 = __builtin_amdgcn_mfma_f32_16x16x32_bf16(bc(ga1), b0, acc0, 0, 0, 0);
            acc1 = __builtin_amdgcn_mfma_f32_16x16x32_bf16(bc(ga1), b1, acc1, 0, 0, 0);
            acc2 = __builtin_amdgcn_mfma_f32_16x16x32_bf16(bc(ga5), b0, acc2, 0, 0, 0);
            acc3 = __builtin_amdgcn_mfma_f32_16x16x32_bf16(bc(ga5), b1, acc3, 0, 0, 0);
            b0 = SB[2 * 64]; b1 = SB[6 * 64];
            acc0 = __builtin_amdgcn_mfma_f32_16x16x32_bf16(bc(ga2), b0, acc0, 0, 0, 0);
            acc1 = __builtin_amdgcn_mfma_f32_16x16x32_bf16(bc(ga2), b1, acc1, 0, 0, 0);
            acc2 = __builtin_amdgcn_mfma_f32_16x16x32_bf16(bc(ga6), b0, acc2, 0, 0, 0);
            acc3 = __builtin_amdgcn_mfma_f32_16x16x32_bf16(bc(ga6), b1, acc3, 0, 0, 0);
            b0 = SB[3 * 64]; b1 = SB[7 * 64];
            acc0 = __builtin_amdgcn_mfma_f32_16x16x32_bf16(bc(ga3), b0, acc0, 0, 0, 0);
            acc1 = __builtin_amdgcn_mfma_f32_16x16x32_bf16(bc(ga3), b1, acc1, 0, 0, 0);
            acc2 = __builtin_amdgcn_mfma_f32_16x16x32_bf16(bc(ga7), b0, acc2, 0, 0, 0);
            acc3 = __builtin_amdgcn_mfma_f32_16x16x32_bf16(bc(ga7), b1, acc3, 0, 0, 0);

            rec2_00 = quadact(acc0, rec2_00, bt2A);
            rec2_01 = quadact(acc1, rec2_01, bt2A);
            rec2_10 = quadact(acc2, rec2_10, bt2B);
            rec2_11 = quadact(acc3, rec2_11, bt2B);
            if (last) {
                *(uint2*)(P0s + wr00) = rec2_00;
                *(uint2*)(P0s + wr01) = rec2_01;
                *(uint2*)(P0s + wr10) = rec2_10;
                *(uint2*)(P0s + wr11) = rec2_11;
            }
            // no barrier on non-last iters (P1 readers protected by post-L0 barrier)
        }
    }
    __syncthreads();

    // ---- output layer: waves 0..3, one 16-px group each; W_out from ws (L2-hot) ----
    if (w < 4) {
        float4 go = *(const float4*)(gammao_s + lg * 4);
        f32x4 oacc{go.x, go.y, go.z, go.w};
        const uint4* OA = wsU + 4096 + l;
        const bf16x8* OB = P0c + (w * 4) * 64 + l;
        oacc = __builtin_amdgcn_mfma_f32_16x16x32_bf16(bc(OA[0 * 64]), OB[0 * 64], oacc, 0, 0, 0);
        oacc = __builtin_amdgcn_mfma_f32_16x16x32_bf16(bc(OA[1 * 64]), OB[1 * 64], oacc, 0, 0, 0);
        oacc = __builtin_amdgcn_mfma_f32_16x16x32_bf16(bc(OA[2 * 64]), OB[2 * 64], oacc, 0, 0, 0);
        oacc = __builtin_amdgcn_mfma_f32_16x16x32_bf16(bc(OA[3 * 64]), OB[3 * 64], oacc, 0, 0, 0);
        int p = pixbase + w * 16 + lr;
        if (lg == 0) {
            out[0 * NPIX + p] = actf(oacc[0]);
            out[1 * NPIX + p] = actf(oacc[1]);
            out[2 * NPIX + p] = actf(oacc[2]);
        }
    }
}

extern "C" void kernel_launch(void* const* d_in, const int* in_sizes, int n_in,
                              void* d_out, int out_size, void* d_ws, size_t ws_size,
                              hipStream_t stream) {
    const float* x_in     = (const float*)d_in[0];
    const float* W_in     = (const float*)d_in[1];
    const float* W_h      = (const float*)d_in[2];
    const float* r_rec    = (const float*)d_in[3];
    const float* resp     = (const float*)d_in[4];
    const float* bias     = (const float*)d_in[5];
    const float* W_out    = (const float*)d_in[6];
    const float* resp_out = (const float*)d_in[7];
    const float* b_out    = (const float*)d_in[8];
    const int*   n_iters  = (const int*)d_in[9];
    float* out = (float*)d_out;
    unsigned short* ws = (unsigned short*)d_ws;

    prep_weights<<<17, 256, 0, stream>>>(W_h, W_out, resp, resp_out, ws);
    fused_net<<<NPIX / PBLK, 512, 0, stream>>>(x_in, W_in, r_rec, resp, bias,
                                               b_out, n_iters, ws, out);
}